// Round 6
// baseline (271.341 us; speedup 1.0000x reference)
//
#include <hip/hip_runtime.h>

// CausalLinearRelativeAttention — chunked 3-branch causal linear attention, bf16 MFMA.
// N=4, L=2048, H=8, D=Dv=128, chunk C=128, T=16 chunks, 3 branches (coeff -2 folded into Qb2).
// R8: dropped kbt3 (-48MB writes). R9: p3 octet-XOR swizzle (conflicts 3.74M -> ~0, p3 off top-5).
// R10: k_kvfeat grid-512 was 2 blocks/CU (grid-limited, 16% occ, 2.4 TB/s — latency-bound).
//      Split by column halves: grid 1024, 16KB LDS tile [128][64], 4 blocks/CU (16 waves).
//      3-term XOR swizzle (q ^ rr>>3 ^ rr&7): conflict-free tile writes AND gather reads.

typedef float f32x4 __attribute__((ext_vector_type(4)));
typedef short s16x8 __attribute__((ext_vector_type(8)));
typedef short s16x4 __attribute__((ext_vector_type(4)));
typedef unsigned short u16;

static constexpr int    Ln   = 2048;
static constexpr size_t NHLD = (size_t)32 * 2048 * 128; // per-branch feature elems = 8,388,608
static constexpr size_t KSB  = (size_t)32 * 16 * 128;   // kspre per-branch stride = 65536

__device__ __forceinline__ float b2f(u16 s) {
  union { unsigned u; float f; } x; x.u = ((unsigned)s) << 16; return x.f;
}
__device__ __forceinline__ u16 f2b(float f) {
  union { float f; unsigned u; } x; x.f = f;
  unsigned r = x.u + 0x7fffu + ((x.u >> 16) & 1u);
  return (u16)(r >> 16);
}
__device__ __forceinline__ s16x8 pack8(f32x4 a, f32x4 b) {
  s16x8 r;
  r[0] = (short)f2b(a[0]); r[1] = (short)f2b(a[1]); r[2] = (short)f2b(a[2]); r[3] = (short)f2b(a[3]);
  r[4] = (short)f2b(b[0]); r[5] = (short)f2b(b[1]); r[6] = (short)f2b(b[2]); r[7] = (short)f2b(b[3]);
  return r;
}

// ---------------------------------------------------------------- K0: omega^T (bf16) + column sums
__global__ __launch_bounds__(256) void k_omega(const float* __restrict__ om,
                                               u16* __restrict__ wt, float* __restrict__ osum) {
  __shared__ alignas(16) u16 T[128][136];
  int h = blockIdx.x, t = threadIdx.x;
  for (int idx = t; idx < 128 * 32; idx += 256) {
    int i = idx >> 5, cs = (idx & 31) << 2;
    f32x4 vv = *(const f32x4*)(om + ((size_t)(h * 128 + i)) * 128 + cs);
    T[i][cs + 0] = f2b(vv[0]); T[i][cs + 1] = f2b(vv[1]);
    T[i][cs + 2] = f2b(vv[2]); T[i][cs + 3] = f2b(vv[3]);
  }
  if (t < 128) { // exact fp32 column sums (coalesced per row)
    float acc = 0.f;
    for (int i = 0; i < 128; i++) acc += om[((size_t)(h * 128 + i)) * 128 + t];
    osum[h * 128 + t] = acc;
  }
  __syncthreads();
  { // transposed write: wt[h][j][i] = omega[h][i][j]
    int j = t >> 1, lh = (t & 1) << 6;
    s16x8* dst = (s16x8*)(wt + ((size_t)(h * 128 + j)) * 128 + lh);
    for (int u = 0; u < 8; u++) {
      s16x8 pv;
#pragma unroll
      for (int e = 0; e < 8; e++) pv[e] = (short)T[lh + u * 8 + e][j];
      dst[u] = pv;
    }
  }
}

// ---------------------- K1 v5: column-half blocks (grid 1024 = 2 per chunk, 16KB LDS, 4 blk/CU).
// kb3 naturals {c^2,s^2,sc} stored DIRECT (128B half-line segments). V^T half-tile [128 s][64 i]
// built with 3-term XOR swizzle and streamed as a contiguous 16KB block.
__global__ __launch_bounds__(256) void k_kvfeat(const float* __restrict__ kg, const float* __restrict__ vg,
                                                const float* __restrict__ klg, const float* __restrict__ osum,
                                                u16* __restrict__ kb3, u16* __restrict__ vt) {
  __shared__ alignas(16) u16 T[128][64]; // V natural half [s][i-half], swizzled granules; 16 KB
  int bid = blockIdx.x, t = threadIdx.x;
  int ih = bid & 1, c = (bid >> 1) & 15, h = (bid >> 5) & 7, n = bid >> 8;
  int l0 = c << 7, nh = (n << 3) + h, ihb = ih << 6;
  const float invL = 1.0f / 2048.0f;
  int q = t & 15, cs = ihb + (q << 2);        // global column quad fixed per thread
  f32x4 osv = *(const f32x4*)(osum + h * 128 + cs);
#pragma unroll
  for (int it = 0; it < 8; it++) {
    int idx = (it << 8) + t;
    int rr = idx >> 4;                        // row in chunk 0..127
    int l = l0 + rr;
    size_t gb = (((size_t)(n * Ln + l) * 8 + h) << 7) + cs;
    f32x4 kv = *(const f32x4*)(kg + gb);
    f32x4 vv = *(const f32x4*)(vg + gb);
    float klv = klg[n * Ln + l];
    float tb = (float)l * invL;
    u16 r0[4], r1[4], r2[4];
#pragma unroll
    for (int e = 0; e < 4; e++) {
      float kf = (kv[e] > 0.f ? kv[e] + 1.f : __expf(kv[e])) * klv;
      float tt = tb * osv[e];
      float s, cc; __sincosf(tt, &s, &cc);
      r0[e] = f2b(kf * cc * cc);
      r1[e] = f2b(kf * s * s);
      r2[e] = f2b(kf * s * cc);
    }
    int gs = ((q ^ (rr >> 3) ^ (rr & 7)) & 15) << 2; // 3-term swizzle: writes AND gathers spread
    *(s16x4*)&T[rr][gs] = (s16x4){(short)f2b(vv[0]), (short)f2b(vv[1]),
                                  (short)f2b(vv[2]), (short)f2b(vv[3])};
    size_t nb = ((size_t)nh * Ln + l) * 128 + cs;
    *(s16x4*)(kb3 + nb)          = (s16x4){(short)r0[0], (short)r0[1], (short)r0[2], (short)r0[3]};
    *(s16x4*)(kb3 + NHLD + nb)   = (s16x4){(short)r1[0], (short)r1[1], (short)r1[2], (short)r1[3]};
    *(s16x4*)(kb3 + 2*NHLD + nb) = (s16x4){(short)r2[0], (short)r2[1], (short)r2[2], (short)r2[3]};
  }
  __syncthreads();
  { // stream V^T half-chunk out: contiguous 16KB (rows i = ihb..ihb+63 of [nh][c][i][sc])
    size_t bv = (((size_t)(nh * 16 + c)) << 14) + ((size_t)ihb << 7);
    for (int idx = t; idx < 1024; idx += 256) {
      int i = idx >> 4, o = idx & 15;         // i = local column 0..63, o = sc-octet
      s16x8 v1;
#pragma unroll
      for (int u = 0; u < 8; u++) {
        int gp = (((((i >> 2) ^ o ^ u) & 15)) << 2) + (i & 3);
        v1[u] = (short)T[(o << 3) + u][gp];
      }
      *(s16x8*)(vt + bv + (((size_t)i) << 7) + (o << 3)) = v1;
    }
  }
}

// ---------------- P1a: per-chunk S^T[j][i] = sum_s V[s,j]*Kb[s,i].
// Kb^T built in LDS from NATURAL kb3: coalesced b128 row loads + column scatter with
// octet-XOR swizzle: logical col s of row r lives at phys col s ^ 8*((r>>3)&7).
__global__ __launch_bounds__(512, 4) void p1a(const u16* __restrict__ vtg, const u16* __restrict__ kb3,
                                              u16* __restrict__ sct, float* __restrict__ ksum) {
  __shared__ alignas(16) u16 B[128][136]; // Kb^T [i][s] (swizzled), later reused for S^T staging
  int bid = blockIdx.x, t = threadIdx.x;
  int c = bid & 15, h = (bid >> 4) & 7, n = (bid >> 7) & 3, b = bid >> 9;
  int l0 = c << 7, nh = (n << 3) + h, bnh = b * 32 + nh;
  int lane = t & 63, quad = lane >> 4, nl = lane & 15, w = t >> 6;
  const u16* kb = kb3 + (size_t)b * NHLD + ((size_t)nh * Ln + l0) * 128;
  for (int idx = t; idx < 2048; idx += 512) {
    int s = idx >> 4, io = idx & 15;          // natural row s, i-octet io
    s16x8 v = *(const s16x8*)(kb + (((size_t)s) << 7) + (io << 3));
    int cp = s ^ ((io & 7) << 3);             // swizzled phys column
#pragma unroll
    for (int j = 0; j < 8; j++) B[(io << 3) + j][cp] = (u16)(short)v[j];
  }
  __syncthreads();
  f32x4 z4 = {0.f, 0.f, 0.f, 0.f};
  f32x4 acc[8];
#pragma unroll
  for (int i = 0; i < 8; i++) acc[i] = z4;
  int arow = (w << 4) + nl; // j row, 8 waves x 16 = 128
  size_t vbase = ((size_t)(nh * 16 + c)) << 14;
  for (int ks = 0; ks < 4; ks++) {
    int k0 = (ks << 5) + (quad << 3);
#pragma unroll
    for (int ct = 0; ct < 8; ct++) {
      int r = (ct << 4) + nl;
      int koff = k0 ^ (((r >> 3) & 7) << 3);  // unswizzle octet
      s16x8 bv = *(const s16x8*)&B[r][koff];
      s16x8 av = *(const s16x8*)(vtg + vbase + (((size_t)arow) << 7) + k0);
      acc[ct] = __builtin_amdgcn_mfma_f32_16x16x32_bf16(av, bv, acc[ct], 0, 0, 0);
    }
  }
  if (t < 128) { // ksum[i] = row-sum of Kb^T row i (swizzle-aware octet reads)
    float s = 0.f;
    int sw = ((t >> 3) & 7) << 3;
#pragma unroll 4
    for (int g = 0; g < 128; g += 8) {
      s16x8 v = *(const s16x8*)&B[t][g ^ sw];
#pragma unroll
      for (int e = 0; e < 8; e++) s += b2f((u16)v[e]);
    }
    ksum[(size_t)(bnh * 16 + c) * 128 + t] = s;
  }
  __syncthreads();
  { // C-layout -> B (as S^T[j][i], plain layout)
    int lbase = (w << 4) + (quad << 2);
#pragma unroll
    for (int ct = 0; ct < 8; ct++) {
      int i = (ct << 4) + nl;
#pragma unroll
      for (int r = 0; r < 4; r++) B[lbase + r][i] = f2b(acc[ct][r]);
    }
  }
  __syncthreads();
  size_t sbase = ((size_t)(bnh * 16 + c)) << 14;
  for (int idx = t; idx < 2048; idx += 512) {
    int jr = idx >> 4, g = (idx & 15) << 3;
    *(s16x8*)(sct + sbase + ((size_t)jr << 7) + g) = *(const s16x8*)&B[jr][g];
  }
}

// ---------------- P1b: in-place exclusive prefix over chunks, vectorized
__global__ __launch_bounds__(256) void p1b(u16* __restrict__ sct, float* __restrict__ ksum) {
  int bid = blockIdx.x, t = threadIdx.x;
  if (bid < 768) {
    int tid = bid * 256 + t;          // 0..196607
    int bnh = tid >> 11, rem = tid & 2047;
    size_t base = ((size_t)bnh << 18) + ((size_t)rem << 3);
    float acc[8] = {0.f, 0.f, 0.f, 0.f, 0.f, 0.f, 0.f, 0.f};
    for (int c = 0; c < 16; c++) {
      size_t a = base + ((size_t)c << 14);
      s16x8 v = *(const s16x8*)(sct + a);
      s16x8 o;
#pragma unroll
      for (int e = 0; e < 8; e++) { o[e] = (short)f2b(acc[e]); acc[e] += b2f((u16)v[e]); }
      *(s16x8*)(sct + a) = o;
    }
  } else {
    int m2 = (bid - 768) * 256 + t;   // 0..12287
    int i = m2 & 127, bnh = m2 >> 7;
    size_t base = (size_t)bnh * 2048 + i;
    float acc = 0.f;
    for (int c = 0; c < 16; c++) {
      size_t a = base + (size_t)c * 128;
      float v = ksum[a];
      ksum[a] = acc;
      acc += v;
    }
  }
}

// ---------------- K2: proj = q2 @ omega (MFMA), Q features + Z_inter fused
// qb3 b-weights {s^2, c^2, -2sc}; zint[nh][l] = sum_b <Qb[l], ksum_prefix_b[c(l)]>
__global__ __launch_bounds__(256, 2) void k_qfeat(const float* __restrict__ q2g, const float* __restrict__ qg,
                                                  const u16* __restrict__ wt, const float* __restrict__ osum,
                                                  const float* __restrict__ kspre,
                                                  u16* __restrict__ qb3, float* __restrict__ zintg) {
  __shared__ alignas(16) u16 B[128][136]; // omega^T[h]; later reused rows 0..63 for sin^2(proj)
  __shared__ float osb[128];
  int bid = blockIdx.x, t = threadIdx.x;
  int m = bid & 31, h = (bid >> 5) & 7, n = bid >> 8;
  int l0 = m << 6, c = m >> 1, nh = (n << 3) + h;
  if (t < 128) osb[t] = osum[h * 128 + t];
  for (int idx = t; idx < 2048; idx += 256) {
    int j = idx >> 4, cs = (idx & 15) << 3;
    *(s16x8*)&B[j][cs] = *(const s16x8*)(wt + ((size_t)(h * 128 + j)) * 128 + cs);
  }
  __syncthreads();
  int lane = t & 63, quad = lane >> 4, nl = lane & 15, w = t >> 6;
  f32x4 z4 = {0.f, 0.f, 0.f, 0.f};
  f32x4 acc[8];
#pragma unroll
  for (int i = 0; i < 8; i++) acc[i] = z4;
  int arow = l0 + (w << 4) + nl;
  for (int ks = 0; ks < 4; ks++) {
    int k0 = (ks << 5) + (quad << 3);
    const float* ap = q2g + (((size_t)(n * Ln + arow) * 8 + h) << 7) + k0;
    s16x8 av = pack8(*(const f32x4*)ap, *(const f32x4*)(ap + 4));
#pragma unroll
    for (int ct = 0; ct < 8; ct++) {
      s16x8 bv = *(const s16x8*)&B[(ct << 4) + nl][k0];
      acc[ct] = __builtin_amdgcn_mfma_f32_16x16x32_bf16(av, bv, acc[ct], 0, 0, 0);
    }
  }
  __syncthreads();
  { // sin^2(proj) -> B rows 0..63
    int lbase = (w << 4) + (quad << 2);
#pragma unroll
    for (int ct = 0; ct < 8; ct++) {
      int j = (ct << 4) + nl;
#pragma unroll
      for (int r = 0; r < 4; r++) {
        float sp = __sinf(acc[ct][r]);
        B[lbase + r][j] = f2b(sp * sp);
      }
    }
  }
  __syncthreads();
  const float invL = 1.0f / 2048.0f;
  for (int idx = t; idx < 1024; idx += 256) {
    int l = idx >> 4, j0 = (idx & 15) << 3, gl = l0 + l;
    s16x8 s2v = *(const s16x8*)&B[l][j0];
    const float* qp = qg + (((size_t)(n * Ln + gl) * 8 + h) << 7) + j0;
    f32x4 qa = *(const f32x4*)qp, qbv = *(const f32x4*)(qp + 4);
    size_t kbb = ((size_t)nh * 16 + c) * 128 + j0;
    f32x4 kp0a = *(const f32x4*)(kspre + kbb),           kp0b = *(const f32x4*)(kspre + kbb + 4);
    f32x4 kp1a = *(const f32x4*)(kspre + kbb + KSB),     kp1b = *(const f32x4*)(kspre + kbb + KSB + 4);
    f32x4 kp2a = *(const f32x4*)(kspre + kbb + 2 * KSB), kp2b = *(const f32x4*)(kspre + kbb + 2 * KSB + 4);
    s16x8 o0, o1, o2;
    float z = 0.f;
    float tb = (float)gl * invL;
#pragma unroll
    for (int e = 0; e < 8; e++) {
      float s2p = b2f((u16)s2v[e]);
      float qv = (e < 4) ? qa[e] : qbv[e - 4];
      float f = qv > 0.f ? qv + 1.f : __expf(qv);
      float Qt = s2p * f;
      float tt = tb * osb[j0 + e];
      float s, cc; __sincosf(tt, &s, &cc);
      float v0 = Qt * s * s, v1 = Qt * cc * cc, v2 = -2.f * Qt * s * cc;
      float k0v = (e < 4) ? kp0a[e] : kp0b[e - 4];
      float k1v = (e < 4) ? kp1a[e] : kp1b[e - 4];
      float k2v = (e < 4) ? kp2a[e] : kp2b[e - 4];
      z += v0 * k0v + v1 * k1v + v2 * k2v;
      o0[e] = (short)f2b(v0); o1[e] = (short)f2b(v1); o2[e] = (short)f2b(v2);
    }
    size_t base = ((size_t)nh * Ln + gl) * 128 + j0;
    *(s16x8*)(qb3 + base)            = o0;
    *(s16x8*)(qb3 + base + NHLD)     = o1;
    *(s16x8*)(qb3 + base + 2 * NHLD) = o2;
    z += __shfl_xor(z, 1); z += __shfl_xor(z, 2);
    z += __shfl_xor(z, 4); z += __shfl_xor(z, 8);
    if (nl == 0) zintg[(size_t)nh * Ln + gl] = z;
  }
}

// ---------------- P3 v2: octet-XOR-swizzled stride-128 tiles (conflict-free MFMA reads),
//                  A-fragments hoisted before the stage barrier.
__global__ __launch_bounds__(512, 4) void p3(const u16* __restrict__ qb3, const u16* __restrict__ kb3,
                                             const u16* __restrict__ vtg, const u16* __restrict__ sct,
                                             const float* __restrict__ zintg, float* __restrict__ outg) {
  __shared__ union {
    struct { alignas(16) u16 T0[128][128]; alignas(16) u16 T1[128][128]; } s;
    alignas(16) float O[128][132];
  } sm;
  int bid = blockIdx.x, t = threadIdx.x;
  int c = bid & 15, h = (bid >> 4) & 7, n = bid >> 7;
  int l0c = c << 7, nh = (n << 3) + h;
  int lane = t & 63, quad = lane >> 4, nl = lane & 15, w = t >> 6;
  f32x4 z4 = {0.f, 0.f, 0.f, 0.f};
  f32x4 accP[8], accO[8];
#pragma unroll
  for (int i = 0; i < 8; i++) { accP[i] = z4; accO[i] = z4; }
  int arow = l0c + (w << 4) + nl;
  for (int b = 0; b < 3; b++) {
    int bnh = b * 32 + nh;
    __syncthreads();
    for (int idx = t; idx < 2048; idx += 512) { // T0 <- Kb chunk [s][i], swizzled octets
      int s = idx >> 4;
      int co = (((idx & 15) ^ (s & 7)) << 3);
      *(s16x8*)&sm.s.T0[s][co] = *(const s16x8*)(kb3 + (((size_t)bnh * Ln + l0c + s) << 7) + ((idx & 15) << 3));
    }
    size_t sbase = ((size_t)(bnh * 16 + c)) << 14;
    for (int idx = t; idx < 2048; idx += 512) { // T1 <- Sprefix^T [j][i], swizzled octets
      int j = idx >> 4;
      int co = (((idx & 15) ^ (j & 7)) << 3);
      *(s16x8*)&sm.s.T1[j][co] = *(const s16x8*)(sct + sbase + ((size_t)j << 7) + ((idx & 15) << 3));
    }
    s16x8 av[4]; // A-fragments issued before the barrier (latency hidden under staging)
#pragma unroll
    for (int ks = 0; ks < 4; ks++)
      av[ks] = *(const s16x8*)(qb3 + (((size_t)bnh * Ln + arow) << 7) + (ks << 5) + (quad << 3));
    __syncthreads();
    for (int ks = 0; ks < 4; ks++) {
      int k0 = (ks << 5) + (quad << 3);
#pragma unroll
      for (int ct = 0; ct < 8; ct++) {
        int r = (ct << 4) + nl;
        int koff = k0 ^ ((r & 7) << 3);       // unswizzle
        s16x8 bv0 = *(const s16x8*)&sm.s.T0[r][koff];
        accP[ct] = __builtin_amdgcn_mfma_f32_16x16x32_bf16(av[ks], bv0, accP[ct], 0, 0, 0);
        s16x8 bv1 = *(const s16x8*)&sm.s.T1[r][koff];
        accO[ct] = __builtin_amdgcn_mfma_f32_16x16x32_bf16(av[ks], bv1, accO[ct], 0, 0, 0);
      }
    }
  }
  __syncthreads();
  // masked P -> T0 as P[l][s] (bf16, swizzled) + register row-sums; stage T1 <- V^T [j][sc]
  float zP[4] = {0.f, 0.f, 0.f, 0.f};
  int lbase = (w << 4) + (quad << 2);
#pragma unroll
  for (int ct = 0; ct < 8; ct++) {
    int ss = (ct << 4) + nl;
#pragma unroll
    for (int r = 0; r < 4; r++) {
      int lr = lbase + r;
      float pv = (ss <= lr) ? accP[ct][r] : 0.f;
      zP[r] += pv;
      sm.s.T0[lr][ss ^ ((lr & 7) << 3)] = f2b(pv);
    }
  }
#pragma unroll
  for (int mteam = 1; mteam <= 8; mteam <<= 1) {
#pragma unroll
    for (int r = 0; r < 4; r++) zP[r] += __shfl_xor(zP[r], mteam);
  }
  size_t vbase = ((size_t)(nh * 16 + c)) << 14;
  for (int idx = t; idx < 2048; idx += 512) { // T1 <- V^T chunk (linear 32KB stream), swizzled
    int j = idx >> 4;
    int co = (((idx & 15) ^ (j & 7)) << 3);
    *(s16x8*)&sm.s.T1[j][co] = *(const s16x8*)(vtg + vbase + ((size_t)idx << 3));
  }
  float zf[4];
#pragma unroll
  for (int r = 0; r < 4; r++)
    zf[r] = zintg[(size_t)nh * Ln + l0c + lbase + r] + zP[r] + 1e-6f;
  __syncthreads();
  // intra: A = masked P (T0 rows l, k=s), B = V^T (T1 rows j, k=s)
  for (int ks = 0; ks < 4; ks++) {
    int k0 = (ks << 5) + (quad << 3);
    int rw = (w << 4) + nl;
    s16x8 pav = *(const s16x8*)&sm.s.T0[rw][k0 ^ ((rw & 7) << 3)];
#pragma unroll
    for (int ct = 0; ct < 8; ct++) {
      int r = (ct << 4) + nl;
      s16x8 vv = *(const s16x8*)&sm.s.T1[r][k0 ^ ((r & 7) << 3)];
      accO[ct] = __builtin_amdgcn_mfma_f32_16x16x32_bf16(pav, vv, accO[ct], 0, 0, 0);
    }
  }
  __syncthreads();
  // divided result -> fp32 LDS overlay (T0/T1 dead now)
#pragma unroll
  for (int ct = 0; ct < 8; ct++) {
    int j = (ct << 4) + nl;
#pragma unroll
    for (int r = 0; r < 4; r++) sm.O[lbase + r][j] = accO[ct][r] / zf[r];
  }
  __syncthreads();
  for (int idx = t; idx < 4096; idx += 512) { // full 512B-row coalesced stores
    int l = idx >> 5, g = (idx & 31) << 2;
    *(f32x4*)(outg + (((size_t)(n * Ln + l0c + l) * 8 + h) << 7) + g) = *(const f32x4*)&sm.O[l][g];
  }
}

extern "C" void kernel_launch(void* const* d_in, const int* in_sizes, int n_in,
                              void* d_out, int out_size, void* d_ws, size_t ws_size,
                              hipStream_t stream) {
  (void)in_sizes; (void)n_in; (void)out_size; (void)ws_size;
  const float* q   = (const float*)d_in[0];
  const float* q2  = (const float*)d_in[1];
  const float* kk  = (const float*)d_in[2];
  const float* vv  = (const float*)d_in[3];
  const float* kl  = (const float*)d_in[4];
  const float* om  = (const float*)d_in[5];
  float* out = (float*)d_out;

  // workspace carve (bf16 region then fp32 region) — compacted, ~171 MB
  u16* W     = (u16*)d_ws;
  u16* qb3   = W;                 // 3*NHLD
  u16* kb3   = W + 3 * NHLD;      // 3*NHLD (naturals; p1a transposes in-kernel)
  u16* vt    = W + 6 * NHLD;      // NHLD   (chunk-blocked [nh][c][i][sc])
  u16* sct   = W + 7 * NHLD;      // 3*NHLD (chunk sums -> exclusive prefix, in place)
  u16* wt    = W + 10 * NHLD;     // 131072 (omega^T bf16)
  float* ks  = (float*)(W + 10 * NHLD + 131072); // 196608 f32 (chunk Ksum -> prefix)
  float* osm = ks + 196608;       // 1024 f32
  float* zin = osm + 1024;        // 65536 f32 (Z_inter)

  k_omega <<<8,    256, 0, stream>>>(om, wt, osm);
  k_kvfeat<<<1024, 256, 0, stream>>>(kk, vv, kl, osm, kb3, vt);
  p1a     <<<1536, 512, 0, stream>>>(vt, kb3, sct, ks);
  p1b     <<<816,  256, 0, stream>>>(sct, ks);
  k_qfeat <<<1024, 256, 0, stream>>>(q2, q, wt, osm, ks, qb3, zin);
  p3      <<<512,  512, 0, stream>>>(qb3, kb3, vt, sct, zin, out);
}

// Round 7
// 269.176 us; speedup vs baseline: 1.0080x; 1.0080x over previous
//
#include <hip/hip_runtime.h>

// CausalLinearRelativeAttention — chunked 3-branch causal linear attention, bf16 MFMA.
// N=4, L=2048, H=8, D=Dv=128, chunk C=128, T=16 chunks, 3 branches (coeff -2 folded into Qb2).
// R8: dropped kbt3 (-48MB writes). R9/R10: p3 swizzle + kvfeat split = NEUTRAL (conflict count
//     identical 3.7M -> conflicts weren't in MFMA reads; totals flat 270-271 for 3 rounds).
// R11: fuse k_kvfeat + p1a -> k_kvs. One block per (n,h,c): features -> kb3/vt stores ->
//     same-block p1a MFMA with kb3/vt re-read SAME-CU L2-HOT (was a cross-kernel round trip).
//     VT-build tile and KT MFMA tile time-share one 35KB LDS union. 6 dispatches -> 5.
//     All arithmetic orders/layouts preserved bit-for-bit; p1b/k_qfeat/p3 untouched.

typedef float f32x4 __attribute__((ext_vector_type(4)));
typedef short s16x8 __attribute__((ext_vector_type(8)));
typedef short s16x4 __attribute__((ext_vector_type(4)));
typedef unsigned short u16;

static constexpr int    Ln   = 2048;
static constexpr size_t NHLD = (size_t)32 * 2048 * 128; // per-branch feature elems = 8,388,608
static constexpr size_t KSB  = (size_t)32 * 16 * 128;   // kspre per-branch stride = 65536

__device__ __forceinline__ float b2f(u16 s) {
  union { unsigned u; float f; } x; x.u = ((unsigned)s) << 16; return x.f;
}
__device__ __forceinline__ u16 f2b(float f) {
  union { float f; unsigned u; } x; x.f = f;
  unsigned r = x.u + 0x7fffu + ((x.u >> 16) & 1u);
  return (u16)(r >> 16);
}
__device__ __forceinline__ s16x8 pack8(f32x4 a, f32x4 b) {
  s16x8 r;
  r[0] = (short)f2b(a[0]); r[1] = (short)f2b(a[1]); r[2] = (short)f2b(a[2]); r[3] = (short)f2b(a[3]);
  r[4] = (short)f2b(b[0]); r[5] = (short)f2b(b[1]); r[6] = (short)f2b(b[2]); r[7] = (short)f2b(b[3]);
  return r;
}

// ---------------------------------------------------------------- K0: omega^T (bf16) + column sums
__global__ __launch_bounds__(256) void k_omega(const float* __restrict__ om,
                                               u16* __restrict__ wt, float* __restrict__ osum) {
  __shared__ alignas(16) u16 T[128][136];
  int h = blockIdx.x, t = threadIdx.x;
  for (int idx = t; idx < 128 * 32; idx += 256) {
    int i = idx >> 5, cs = (idx & 31) << 2;
    f32x4 vv = *(const f32x4*)(om + ((size_t)(h * 128 + i)) * 128 + cs);
    T[i][cs + 0] = f2b(vv[0]); T[i][cs + 1] = f2b(vv[1]);
    T[i][cs + 2] = f2b(vv[2]); T[i][cs + 3] = f2b(vv[3]);
  }
  if (t < 128) { // exact fp32 column sums (coalesced per row)
    float acc = 0.f;
    for (int i = 0; i < 128; i++) acc += om[((size_t)(h * 128 + i)) * 128 + t];
    osum[h * 128 + t] = acc;
  }
  __syncthreads();
  { // transposed write: wt[h][j][i] = omega[h][i][j]
    int j = t >> 1, lh = (t & 1) << 6;
    s16x8* dst = (s16x8*)(wt + ((size_t)(h * 128 + j)) * 128 + lh);
    for (int u = 0; u < 8; u++) {
      s16x8 pv;
#pragma unroll
      for (int e = 0; e < 8; e++) pv[e] = (short)T[lh + u * 8 + e][j];
      dst[u] = pv;
    }
  }
}

// ---------------------- K1+P1a fused (k_kvs): one block per (n,h,c), 512 threads.
// Phase A: features (trig) -> kb3 naturals direct + VT build tile (granule-XOR swizzle).
// Phase B: stream vt out (contiguous 32KB).
// Phase C (x3 branches): KT <- kb3 chunk (L2-hot re-read, p1a column-scatter octet swizzle),
//   S^T MFMA (A = vt rows, L2-hot), ksum rowsum, restage S^T, stream sct out.
// VT and KT time-share one LDS union (~35KB).
__global__ __launch_bounds__(512) void k_kvs(const float* __restrict__ kg, const float* __restrict__ vg,
                                             const float* __restrict__ klg, const float* __restrict__ osum,
                                             u16* __restrict__ kb3, u16* __restrict__ vt,
                                             u16* __restrict__ sct, float* __restrict__ ksum) {
  __shared__ union {
    alignas(16) u16 VT[128][128]; // V natural [s][i], swizzled granules (phase A/B)
    alignas(16) u16 KT[128][136]; // Kb^T [i][s] swizzled; then S^T staging (phase C)
  } sm;
  int bid = blockIdx.x, t = threadIdx.x;
  int c = bid & 15, h = (bid >> 4) & 7, n = bid >> 7;
  int l0 = c << 7, nh = (n << 3) + h;
  const float invL = 1.0f / 2048.0f;
  int gcol = t & 31, cs = gcol << 2;          // column quad fixed per thread
  f32x4 osv = *(const f32x4*)(osum + h * 128 + cs);
  // ---- phase A: features + kb3 direct stores + VT build
#pragma unroll
  for (int it = 0; it < 8; it++) {
    int rr = (it << 4) + (t >> 5);            // row in chunk 0..127
    int l = l0 + rr;
    size_t gb = (((size_t)(n * Ln + l) * 8 + h) << 7) + cs;
    f32x4 kv = *(const f32x4*)(kg + gb);
    f32x4 vv = *(const f32x4*)(vg + gb);
    float klv = klg[n * Ln + l];
    float tb = (float)l * invL;
    u16 r0[4], r1[4], r2[4];
#pragma unroll
    for (int e = 0; e < 4; e++) {
      float kf = (kv[e] > 0.f ? kv[e] + 1.f : __expf(kv[e])) * klv;
      float tt = tb * osv[e];
      float s, cc; __sincosf(tt, &s, &cc);
      r0[e] = f2b(kf * cc * cc);
      r1[e] = f2b(kf * s * s);
      r2[e] = f2b(kf * s * cc);
    }
    int gs = (gcol ^ (rr >> 3)) << 2;         // swizzled granule (4 u16)
    *(s16x4*)&sm.VT[rr][gs] = (s16x4){(short)f2b(vv[0]), (short)f2b(vv[1]),
                                      (short)f2b(vv[2]), (short)f2b(vv[3])};
    size_t nb = ((size_t)nh * Ln + l) * 128 + cs;
    *(s16x4*)(kb3 + nb)          = (s16x4){(short)r0[0], (short)r0[1], (short)r0[2], (short)r0[3]};
    *(s16x4*)(kb3 + NHLD + nb)   = (s16x4){(short)r1[0], (short)r1[1], (short)r1[2], (short)r1[3]};
    *(s16x4*)(kb3 + 2*NHLD + nb) = (s16x4){(short)r2[0], (short)r2[1], (short)r2[2], (short)r2[3]};
  }
  __syncthreads();
  // ---- phase B: stream V^T chunk out (contiguous 32KB, full-line writes)
  size_t bv = ((size_t)(nh * 16 + c)) << 14;
  for (int idx = t; idx < 2048; idx += 512) {
    int i = idx >> 4, o = idx & 15;
    int gp = (((i >> 2) ^ o) << 2) + (i & 3);
    s16x8 v1;
#pragma unroll
    for (int u = 0; u < 8; u++) v1[u] = (short)sm.VT[(o << 3) + u][gp];
    *(s16x8*)(vt + bv + (((size_t)i) << 7) + (o << 3)) = v1;
  }
  // ---- phase C: per-branch chunk-S^T (p1a body, operands L2-hot)
  int lane = t & 63, quad = lane >> 4, nl = lane & 15, w = t >> 6;
  int arow = (w << 4) + nl;                   // j row, 8 waves x 16 = 128
  const u16* vchunk = vt + bv;
  for (int b = 0; b < 3; b++) {
    int bnh = b * 32 + nh;
    const u16* kb = kb3 + (size_t)b * NHLD + ((size_t)nh * Ln + l0) * 128;
    __syncthreads();                          // VT reads / prev sct stream done before KT overwrite
    for (int idx = t; idx < 2048; idx += 512) {
      int s = idx >> 4, io = idx & 15;        // natural row s, i-octet io
      s16x8 v = *(const s16x8*)(kb + (((size_t)s) << 7) + (io << 3)); // L2-hot (own writes)
      int cp = s ^ ((io & 7) << 3);           // swizzled phys column
#pragma unroll
      for (int j = 0; j < 8; j++) sm.KT[(io << 3) + j][cp] = (u16)(short)v[j];
    }
    __syncthreads();
    f32x4 z4 = {0.f, 0.f, 0.f, 0.f};
    f32x4 acc[8];
#pragma unroll
    for (int i = 0; i < 8; i++) acc[i] = z4;
    for (int ks = 0; ks < 4; ks++) {
      int k0 = (ks << 5) + (quad << 3);
      s16x8 av = *(const s16x8*)(vchunk + (((size_t)arow) << 7) + k0); // L2-hot
#pragma unroll
      for (int ct = 0; ct < 8; ct++) {
        int r = (ct << 4) + nl;
        int koff = k0 ^ (((r >> 3) & 7) << 3); // unswizzle octet
        s16x8 bvv = *(const s16x8*)&sm.KT[r][koff];
        acc[ct] = __builtin_amdgcn_mfma_f32_16x16x32_bf16(av, bvv, acc[ct], 0, 0, 0);
      }
    }
    if (t < 128) { // ksum[i] = row-sum of Kb^T row i (swizzle-aware octet reads)
      float s = 0.f;
      int sw = ((t >> 3) & 7) << 3;
#pragma unroll 4
      for (int g = 0; g < 128; g += 8) {
        s16x8 v = *(const s16x8*)&sm.KT[t][g ^ sw];
#pragma unroll
        for (int e = 0; e < 8; e++) s += b2f((u16)v[e]);
      }
      ksum[(size_t)(bnh * 16 + c) * 128 + t] = s;
    }
    __syncthreads();
    { // C-layout -> KT (as S^T[j][i], plain layout)
      int lbase = (w << 4) + (quad << 2);
#pragma unroll
      for (int ct = 0; ct < 8; ct++) {
        int i = (ct << 4) + nl;
#pragma unroll
        for (int r = 0; r < 4; r++) sm.KT[lbase + r][i] = f2b(acc[ct][r]);
      }
    }
    __syncthreads();
    size_t sbase = ((size_t)(bnh * 16 + c)) << 14;
    for (int idx = t; idx < 2048; idx += 512) {
      int jr = idx >> 4, g = (idx & 15) << 3;
      *(s16x8*)(sct + sbase + ((size_t)jr << 7) + g) = *(const s16x8*)&sm.KT[jr][g];
    }
  }
}

// ---------------- P1b: in-place exclusive prefix over chunks, vectorized
__global__ __launch_bounds__(256) void p1b(u16* __restrict__ sct, float* __restrict__ ksum) {
  int bid = blockIdx.x, t = threadIdx.x;
  if (bid < 768) {
    int tid = bid * 256 + t;          // 0..196607
    int bnh = tid >> 11, rem = tid & 2047;
    size_t base = ((size_t)bnh << 18) + ((size_t)rem << 3);
    float acc[8] = {0.f, 0.f, 0.f, 0.f, 0.f, 0.f, 0.f, 0.f};
    for (int c = 0; c < 16; c++) {
      size_t a = base + ((size_t)c << 14);
      s16x8 v = *(const s16x8*)(sct + a);
      s16x8 o;
#pragma unroll
      for (int e = 0; e < 8; e++) { o[e] = (short)f2b(acc[e]); acc[e] += b2f((u16)v[e]); }
      *(s16x8*)(sct + a) = o;
    }
  } else {
    int m2 = (bid - 768) * 256 + t;   // 0..12287
    int i = m2 & 127, bnh = m2 >> 7;
    size_t base = (size_t)bnh * 2048 + i;
    float acc = 0.f;
    for (int c = 0; c < 16; c++) {
      size_t a = base + (size_t)c * 128;
      float v = ksum[a];
      ksum[a] = acc;
      acc += v;
    }
  }
}

// ---------------- K2: proj = q2 @ omega (MFMA), Q features + Z_inter fused
// qb3 b-weights {s^2, c^2, -2sc}; zint[nh][l] = sum_b <Qb[l], ksum_prefix_b[c(l)]>
__global__ __launch_bounds__(256, 2) void k_qfeat(const float* __restrict__ q2g, const float* __restrict__ qg,
                                                  const u16* __restrict__ wt, const float* __restrict__ osum,
                                                  const float* __restrict__ kspre,
                                                  u16* __restrict__ qb3, float* __restrict__ zintg) {
  __shared__ alignas(16) u16 B[128][136]; // omega^T[h]; later reused rows 0..63 for sin^2(proj)
  __shared__ float osb[128];
  int bid = blockIdx.x, t = threadIdx.x;
  int m = bid & 31, h = (bid >> 5) & 7, n = bid >> 8;
  int l0 = m << 6, c = m >> 1, nh = (n << 3) + h;
  if (t < 128) osb[t] = osum[h * 128 + t];
  for (int idx = t; idx < 2048; idx += 256) {
    int j = idx >> 4, cs = (idx & 15) << 3;
    *(s16x8*)&B[j][cs] = *(const s16x8*)(wt + ((size_t)(h * 128 + j)) * 128 + cs);
  }
  __syncthreads();
  int lane = t & 63, quad = lane >> 4, nl = lane & 15, w = t >> 6;
  f32x4 z4 = {0.f, 0.f, 0.f, 0.f};
  f32x4 acc[8];
#pragma unroll
  for (int i = 0; i < 8; i++) acc[i] = z4;
  int arow = l0 + (w << 4) + nl;
  for (int ks = 0; ks < 4; ks++) {
    int k0 = (ks << 5) + (quad << 3);
    const float* ap = q2g + (((size_t)(n * Ln + arow) * 8 + h) << 7) + k0;
    s16x8 av = pack8(*(const f32x4*)ap, *(const f32x4*)(ap + 4));
#pragma unroll
    for (int ct = 0; ct < 8; ct++) {
      s16x8 bv = *(const s16x8*)&B[(ct << 4) + nl][k0];
      acc[ct] = __builtin_amdgcn_mfma_f32_16x16x32_bf16(av, bv, acc[ct], 0, 0, 0);
    }
  }
  __syncthreads();
  { // sin^2(proj) -> B rows 0..63
    int lbase = (w << 4) + (quad << 2);
#pragma unroll
    for (int ct = 0; ct < 8; ct++) {
      int j = (ct << 4) + nl;
#pragma unroll
      for (int r = 0; r < 4; r++) {
        float sp = __sinf(acc[ct][r]);
        B[lbase + r][j] = f2b(sp * sp);
      }
    }
  }
  __syncthreads();
  const float invL = 1.0f / 2048.0f;
  for (int idx = t; idx < 1024; idx += 256) {
    int l = idx >> 4, j0 = (idx & 15) << 3, gl = l0 + l;
    s16x8 s2v = *(const s16x8*)&B[l][j0];
    const float* qp = qg + (((size_t)(n * Ln + gl) * 8 + h) << 7) + j0;
    f32x4 qa = *(const f32x4*)qp, qbv = *(const f32x4*)(qp + 4);
    size_t kbb = ((size_t)nh * 16 + c) * 128 + j0;
    f32x4 kp0a = *(const f32x4*)(kspre + kbb),           kp0b = *(const f32x4*)(kspre + kbb + 4);
    f32x4 kp1a = *(const f32x4*)(kspre + kbb + KSB),     kp1b = *(const f32x4*)(kspre + kbb + KSB + 4);
    f32x4 kp2a = *(const f32x4*)(kspre + kbb + 2 * KSB), kp2b = *(const f32x4*)(kspre + kbb + 2 * KSB + 4);
    s16x8 o0, o1, o2;
    float z = 0.f;
    float tb = (float)gl * invL;
#pragma unroll
    for (int e = 0; e < 8; e++) {
      float s2p = b2f((u16)s2v[e]);
      float qv = (e < 4) ? qa[e] : qbv[e - 4];
      float f = qv > 0.f ? qv + 1.f : __expf(qv);
      float Qt = s2p * f;
      float tt = tb * osb[j0 + e];
      float s, cc; __sincosf(tt, &s, &cc);
      float v0 = Qt * s * s, v1 = Qt * cc * cc, v2 = -2.f * Qt * s * cc;
      float k0v = (e < 4) ? kp0a[e] : kp0b[e - 4];
      float k1v = (e < 4) ? kp1a[e] : kp1b[e - 4];
      float k2v = (e < 4) ? kp2a[e] : kp2b[e - 4];
      z += v0 * k0v + v1 * k1v + v2 * k2v;
      o0[e] = (short)f2b(v0); o1[e] = (short)f2b(v1); o2[e] = (short)f2b(v2);
    }
    size_t base = ((size_t)nh * Ln + gl) * 128 + j0;
    *(s16x8*)(qb3 + base)            = o0;
    *(s16x8*)(qb3 + base + NHLD)     = o1;
    *(s16x8*)(qb3 + base + 2 * NHLD) = o2;
    z += __shfl_xor(z, 1); z += __shfl_xor(z, 2);
    z += __shfl_xor(z, 4); z += __shfl_xor(z, 8);
    if (nl == 0) zintg[(size_t)nh * Ln + gl] = z;
  }
}

// ---------------- P3: octet-XOR-swizzled stride-128 tiles, A-fragments hoisted pre-barrier.
__global__ __launch_bounds__(512, 4) void p3(const u16* __restrict__ qb3, const u16* __restrict__ kb3,
                                             const u16* __restrict__ vtg, const u16* __restrict__ sct,
                                             const float* __restrict__ zintg, float* __restrict__ outg) {
  __shared__ union {
    struct { alignas(16) u16 T0[128][128]; alignas(16) u16 T1[128][128]; } s;
    alignas(16) float O[128][132];
  } sm;
  int bid = blockIdx.x, t = threadIdx.x;
  int c = bid & 15, h = (bid >> 4) & 7, n = bid >> 7;
  int l0c = c << 7, nh = (n << 3) + h;
  int lane = t & 63, quad = lane >> 4, nl = lane & 15, w = t >> 6;
  f32x4 z4 = {0.f, 0.f, 0.f, 0.f};
  f32x4 accP[8], accO[8];
#pragma unroll
  for (int i = 0; i < 8; i++) { accP[i] = z4; accO[i] = z4; }
  int arow = l0c + (w << 4) + nl;
  for (int b = 0; b < 3; b++) {
    int bnh = b * 32 + nh;
    __syncthreads();
    for (int idx = t; idx < 2048; idx += 512) { // T0 <- Kb chunk [s][i], swizzled octets
      int s = idx >> 4;
      int co = (((idx & 15) ^ (s & 7)) << 3);
      *(s16x8*)&sm.s.T0[s][co] = *(const s16x8*)(kb3 + (((size_t)bnh * Ln + l0c + s) << 7) + ((idx & 15) << 3));
    }
    size_t sbase = ((size_t)(bnh * 16 + c)) << 14;
    for (int idx = t; idx < 2048; idx += 512) { // T1 <- Sprefix^T [j][i], swizzled octets
      int j = idx >> 4;
      int co = (((idx & 15) ^ (j & 7)) << 3);
      *(s16x8*)&sm.s.T1[j][co] = *(const s16x8*)(sct + sbase + ((size_t)j << 7) + ((idx & 15) << 3));
    }
    s16x8 av[4]; // A-fragments issued before the barrier (latency hidden under staging)
#pragma unroll
    for (int ks = 0; ks < 4; ks++)
      av[ks] = *(const s16x8*)(qb3 + (((size_t)bnh * Ln + arow) << 7) + (ks << 5) + (quad << 3));
    __syncthreads();
    for (int ks = 0; ks < 4; ks++) {
      int k0 = (ks << 5) + (quad << 3);
#pragma unroll
      for (int ct = 0; ct < 8; ct++) {
        int r = (ct << 4) + nl;
        int koff = k0 ^ ((r & 7) << 3);       // unswizzle
        s16x8 bv0 = *(const s16x8*)&sm.s.T0[r][koff];
        accP[ct] = __builtin_amdgcn_mfma_f32_16x16x32_bf16(av[ks], bv0, accP[ct], 0, 0, 0);
        s16x8 bv1 = *(const s16x8*)&sm.s.T1[r][koff];
        accO[ct] = __builtin_amdgcn_mfma_f32_16x16x32_bf16(av[ks], bv1, accO[ct], 0, 0, 0);
      }
    }
  }
  __syncthreads();
  // masked P -> T0 as P[l][s] (bf16, swizzled) + register row-sums; stage T1 <- V^T [j][sc]
  float zP[4] = {0.f, 0.f, 0.f, 0.f};
  int lbase = (w << 4) + (quad << 2);
#pragma unroll
  for (int ct = 0; ct < 8; ct++) {
    int ss = (ct << 4) + nl;
#pragma unroll
    for (int r = 0; r < 4; r++) {
      int lr = lbase + r;
      float pv = (ss <= lr) ? accP[ct][r] : 0.f;
      zP[r] += pv;
      sm.s.T0[lr][ss ^ ((lr & 7) << 3)] = f2b(pv);
    }
  }
#pragma unroll
  for (int mteam = 1; mteam <= 8; mteam <<= 1) {
#pragma unroll
    for (int r = 0; r < 4; r++) zP[r] += __shfl_xor(zP[r], mteam);
  }
  size_t vbase = ((size_t)(nh * 16 + c)) << 14;
  for (int idx = t; idx < 2048; idx += 512) { // T1 <- V^T chunk (linear 32KB stream), swizzled
    int j = idx >> 4;
    int co = (((idx & 15) ^ (j & 7)) << 3);
    *(s16x8*)&sm.s.T1[j][co] = *(const s16x8*)(vtg + vbase + ((size_t)idx << 3));
  }
  float zf[4];
#pragma unroll
  for (int r = 0; r < 4; r++)
    zf[r] = zintg[(size_t)nh * Ln + l0c + lbase + r] + zP[r] + 1e-6f;
  __syncthreads();
  // intra: A = masked P (T0 rows l, k=s), B = V^T (T1 rows j, k=s)
  for (int ks = 0; ks < 4; ks++) {
    int k0 = (ks << 5) + (quad << 3);
    int rw = (w << 4) + nl;
    s16x8 pav = *(const s16x8*)&sm.s.T0[rw][k0 ^ ((rw & 7) << 3)];
#pragma unroll
    for (int ct = 0; ct < 8; ct++) {
      int r = (ct << 4) + nl;
      s16x8 vv = *(const s16x8*)&sm.s.T1[r][k0 ^ ((r & 7) << 3)];
      accO[ct] = __builtin_amdgcn_mfma_f32_16x16x32_bf16(pav, vv, accO[ct], 0, 0, 0);
    }
  }
  __syncthreads();
  // divided result -> fp32 LDS overlay (T0/T1 dead now)
#pragma unroll
  for (int ct = 0; ct < 8; ct++) {
    int j = (ct << 4) + nl;
#pragma unroll
    for (int r = 0; r < 4; r++) sm.O[lbase + r][j] = accO[ct][r] / zf[r];
  }
  __syncthreads();
  for (int idx = t; idx < 4096; idx += 512) { // full 512B-row coalesced stores
    int l = idx >> 5, g = (idx & 31) << 2;
    *(f32x4*)(outg + (((size_t)(n * Ln + l0c + l) * 8 + h) << 7) + g) = *(const f32x4*)&sm.O[l][g];
  }
}

extern "C" void kernel_launch(void* const* d_in, const int* in_sizes, int n_in,
                              void* d_out, int out_size, void* d_ws, size_t ws_size,
                              hipStream_t stream) {
  (void)in_sizes; (void)n_in; (void)out_size; (void)ws_size;
  const float* q   = (const float*)d_in[0];
  const float* q2  = (const float*)d_in[1];
  const float* kk  = (const float*)d_in[2];
  const float* vv  = (const float*)d_in[3];
  const float* kl  = (const float*)d_in[4];
  const float* om  = (const float*)d_in[5];
  float* out = (float*)d_out;

  // workspace carve (bf16 region then fp32 region) — ~171 MB
  u16* W     = (u16*)d_ws;
  u16* qb3   = W;                 // 3*NHLD
  u16* kb3   = W + 3 * NHLD;      // 3*NHLD (naturals; k_kvs transposes in-block, L2-hot)
  u16* vt    = W + 6 * NHLD;      // NHLD   (chunk-blocked [nh][c][i][sc])
  u16* sct   = W + 7 * NHLD;      // 3*NHLD (chunk sums -> exclusive prefix, in place)
  u16* wt    = W + 10 * NHLD;     // 131072 (omega^T bf16)
  float* ks  = (float*)(W + 10 * NHLD + 131072); // 196608 f32 (chunk Ksum -> prefix)
  float* osm = ks + 196608;       // 1024 f32
  float* zin = osm + 1024;        // 65536 f32 (Z_inter)

  k_omega <<<8,    256, 0, stream>>>(om, wt, osm);
  k_kvs   <<<512,  512, 0, stream>>>(kk, vv, kl, osm, kb3, vt, sct, ks);
  p1b     <<<816,  256, 0, stream>>>(sct, ks);
  k_qfeat <<<1024, 256, 0, stream>>>(q2, q, wt, osm, ks, qb3, zin);
  p3      <<<512,  512, 0, stream>>>(qb3, kb3, vt, sct, zin, out);
}